// Round 10
// baseline (177.263 us; speedup 1.0000x reference)
//
#include <hip/hip_runtime.h>

#define NN 50000
#define NE 800000
#define KF 256
#define MF 64

#define NBK 782    // node buckets of 64: ceil(50000/64)
#define HB 49      // hist/scatter blocks
#define EPB 16384  // edges per hist/scatter block (49*16384 >= 800000)
#define GB 782     // gemm blocks
#define CAP 1536   // LDS edge capacity per bucket (mean 1023 + ~16 sigma)
#define EIDX_CAP (NE + 16 * NBK)

typedef __attribute__((ext_vector_type(8))) short short8;
typedef __attribute__((ext_vector_type(4))) float f32x4;

static __device__ __forceinline__ unsigned short f2bf(float x) {
  unsigned int u = __float_as_uint(x);
  u += 0x7FFF + ((u >> 16) & 1);  // round-nearest-even
  return (unsigned short)(u >> 16);
}
static __device__ __forceinline__ float bf2f(unsigned short u) {
  return __uint_as_float(((unsigned int)u) << 16);
}

// ------- Fused: edge histogram (blocks 0..48) + W prepack (block 49) -------
__global__ __launch_bounds__(1024) void hist_prepack(
    const int* __restrict__ dst, int* __restrict__ histT,
    const float* __restrict__ W, unsigned short* __restrict__ wtab) {
  const int t = threadIdx.x;
  if (blockIdx.x == HB) {  // ---- prepack branch ----
    for (int f = t; f < 2048; f += 1024) {
      const int m = f & 15;
      const int quad = (f >> 4) & 3;
      const int nt = (f >> 6) & 3;
      const int k0i = f >> 8;
      const int n = nt * 16 + m;
      const int kb = k0i * 32 + quad * 8;
      short8 p;
#pragma unroll
      for (int j = 0; j < 8; ++j) p[j] = (short)f2bf(W[(kb + j) * MF + n]);
      *(short8*)(wtab + (size_t)f * 8) = p;
    }
    return;
  }
  __shared__ int hh[NBK];
  for (int i = t; i < NBK; i += 1024) hh[i] = 0;
  __syncthreads();
  const int base = blockIdx.x * EPB;
#pragma unroll
  for (int i = 0; i < EPB / 1024; ++i) {
    const int e = base + i * 1024 + t;
    if (e < NE) atomicAdd(&hh[dst[e] >> 6], 1);
  }
  __syncthreads();
  for (int i = t; i < NBK; i += 1024) histT[i * 64 + blockIdx.x] = hh[i];
}

// ------- Scatter with integrated scan -------------------------------------
__global__ __launch_bounds__(1024) void scatter_scan(
    const int* __restrict__ src, const int* __restrict__ dst,
    const int* __restrict__ histT, int* __restrict__ eidx,
    int* __restrict__ bucketStart, int* __restrict__ bucketCnt) {
  __shared__ int s[1024];
  __shared__ int cur[NBK];
  const int t = threadIdx.x;
  int tot = 0, mine = 0;
  if (t < NBK) {
    const int* hp = histT + t * 64;
#pragma unroll
    for (int b = 0; b < HB; ++b) {
      const int v = hp[b];
      if (b < (int)blockIdx.x) mine += v;
      tot += v;
    }
  }
  const int pad = (tot + 15) & ~15;  // 64 B-align bucket regions
  s[t] = (t < NBK) ? pad : 0;
  __syncthreads();
  for (int off = 1; off < 1024; off <<= 1) {
    const int a = (t >= off) ? s[t - off] : 0;
    __syncthreads();
    s[t] += a;
    __syncthreads();
  }
  if (t < NBK) {
    const int start = s[t] - pad;
    cur[t] = start + mine;
    if (blockIdx.x == 0) {
      bucketStart[t] = start;
      bucketCnt[t] = tot;
    }
  }
  __syncthreads();
  const int base = blockIdx.x * EPB;
#pragma unroll
  for (int i = 0; i < EPB / 1024; ++i) {
    const int e = base + i * 1024 + t;
    if (e < NE) {
      const int d = dst[e];
      const int pos = atomicAdd(&cur[d >> 6], 1);
      eidx[pos] = (src[e] << 6) | (d & 63);
    }
  }
}

// ------- LDS-free MFMA GEMM, batched A-preload pinned by sched_barrier -----
__global__ __launch_bounds__(256, 4) void gemm_mfma(
    const float* __restrict__ h, const unsigned short* __restrict__ wtab,
    const float* __restrict__ norm, unsigned short* __restrict__ hwb) {
  const int t = threadIdx.x;
  const int lane = t & 63;
  const int wv = t >> 6;       // 0..3
  const int m = lane & 15;
  const int quad = lane >> 4;  // 0..3
  const int row0 = blockIdx.x * 64;
  const int arow = row0 + wv * 16 + m;
  const int rowc = (arow < NN) ? arow : (NN - 1);  // clamp; store is guarded
  const float4* ap = (const float4*)(h + (size_t)rowc * KF + quad * 8);

  float4 a[16];
#pragma unroll
  for (int k = 0; k < 8; ++k) {
    a[2 * k] = ap[k * 8];      // k-step stride: 32 floats = 8 float4
    a[2 * k + 1] = ap[k * 8 + 1];
  }
  __builtin_amdgcn_sched_barrier(0);  // all 16 loads stay above this line

  short8 af[8];
#pragma unroll
  for (int k = 0; k < 8; ++k) {
    const float4 a0 = a[2 * k];
    const float4 a1 = a[2 * k + 1];
    af[k][0] = (short)f2bf(a0.x); af[k][1] = (short)f2bf(a0.y);
    af[k][2] = (short)f2bf(a0.z); af[k][3] = (short)f2bf(a0.w);
    af[k][4] = (short)f2bf(a1.x); af[k][5] = (short)f2bf(a1.y);
    af[k][6] = (short)f2bf(a1.z); af[k][7] = (short)f2bf(a1.w);
  }
  __builtin_amdgcn_sched_barrier(0);  // converts complete before MFMA loop

  f32x4 acc[4];
#pragma unroll
  for (int i = 0; i < 4; ++i) acc[i] = (f32x4){0.f, 0.f, 0.f, 0.f};

  const short8* wp = (const short8*)wtab;
#pragma unroll
  for (int k0i = 0; k0i < 8; ++k0i) {
    const short8* wk = wp + k0i * 4 * 64 + lane;
#pragma unroll
    for (int nt = 0; nt < 4; ++nt) {
      const short8 bf = wk[nt * 64];  // L1/L2-resident 32 KB table
      acc[nt] = __builtin_amdgcn_mfma_f32_16x16x32_bf16(af[k0i], bf, acc[nt], 0, 0, 0);
    }
  }

  // Epilogue: D row = quad*4 + r, col = nt*16 + m
  const int gm0 = row0 + wv * 16 + quad * 4;
  float nrm[4];
#pragma unroll
  for (int r = 0; r < 4; ++r) nrm[r] = (gm0 + r < NN) ? norm[gm0 + r] : 0.f;
#pragma unroll
  for (int nt = 0; nt < 4; ++nt) {
#pragma unroll
    for (int r = 0; r < 4; ++r) {
      const int gm = gm0 + r;
      if (gm < NN) hwb[(size_t)gm * MF + nt * 16 + m] = f2bf(acc[nt][r] * nrm[r]);
    }
  }
}

// ------- Fused per-bucket counting sort (in LDS) + gather + epilogue -------
// One block per 64-node bucket. Sorted edge ids stay in LDS (no eidx2
// round-trip); guaranteed-correct global fallback if cnt > CAP.
__global__ __launch_bounds__(256) void sort_gather(
    const int* __restrict__ bucketStart, const int* __restrict__ bucketCnt,
    const int* __restrict__ eidx, int* __restrict__ eidx2,
    const unsigned short* __restrict__ hwb, const float* __restrict__ norm,
    const float* __restrict__ bias, float* __restrict__ out) {
  __shared__ int hcnt[64];   // histogram -> node end (after scan)
  __shared__ int sBeg[64];   // node start (local)
  __shared__ int sCur[64];
  __shared__ int sE[CAP];
  const int t = threadIdx.x;
  const int g = blockIdx.x;
  const int beg = __builtin_amdgcn_readfirstlane(bucketStart[g]);
  const int cnt = __builtin_amdgcn_readfirstlane(bucketCnt[g]);
  if (t < 64) hcnt[t] = 0;
  __syncthreads();
  for (int i = t; i < cnt; i += 256) atomicAdd(&hcnt[eidx[beg + i] & 63], 1);
  __syncthreads();
  if (t < 64) {  // wave 0: exclusive scan of 64 counts
    const int v = hcnt[t];
    int incl = v;
#pragma unroll
    for (int off = 1; off < 64; off <<= 1) {
      const int u = __shfl_up(incl, off, 64);
      if (t >= off) incl += u;
    }
    const int excl = incl - v;
    sBeg[t] = excl;
    sCur[t] = excl;
    hcnt[t] = excl + v;  // end
  }
  __syncthreads();
  const bool inLds = (cnt <= CAP);
  for (int i = t; i < cnt; i += 256) {
    const int val = eidx[beg + i];
    const int p = atomicAdd(&sCur[val & 63], 1);
    if (inLds) sE[p] = val >> 6;
    else eidx2[beg + p] = val >> 6;
  }
  __syncthreads();

  const int lane = t & 63;
  const int wv = t >> 6;  // 0..3; wave handles nodes wv, wv+4, ...
  const float bi = bias[lane];
  for (int nl = wv; nl < 64; nl += 4) {
    const int vtx = g * 64 + nl;
    if (vtx >= NN) break;
    const int s0i = __builtin_amdgcn_readfirstlane(sBeg[nl]);
    const int e0i = __builtin_amdgcn_readfirstlane(hcnt[nl]);
    float acc = 0.f;
    int i = s0i;
    if (inLds) {
      for (; i + 8 <= e0i; i += 8) {  // 8 row-loads in flight
        const int s0 = sE[i], s1 = sE[i + 1], s2 = sE[i + 2], s3 = sE[i + 3];
        const int s4 = sE[i + 4], s5 = sE[i + 5], s6 = sE[i + 6], s7 = sE[i + 7];
        const unsigned short x0 = hwb[(size_t)s0 * MF + lane];
        const unsigned short x1 = hwb[(size_t)s1 * MF + lane];
        const unsigned short x2 = hwb[(size_t)s2 * MF + lane];
        const unsigned short x3 = hwb[(size_t)s3 * MF + lane];
        const unsigned short x4 = hwb[(size_t)s4 * MF + lane];
        const unsigned short x5 = hwb[(size_t)s5 * MF + lane];
        const unsigned short x6 = hwb[(size_t)s6 * MF + lane];
        const unsigned short x7 = hwb[(size_t)s7 * MF + lane];
        acc += bf2f(x0); acc += bf2f(x1); acc += bf2f(x2); acc += bf2f(x3);
        acc += bf2f(x4); acc += bf2f(x5); acc += bf2f(x6); acc += bf2f(x7);
      }
      for (; i < e0i; ++i) acc += bf2f(hwb[(size_t)sE[i] * MF + lane]);
    } else {
      for (; i + 8 <= e0i; i += 8) {
        const int s0 = eidx2[beg + i], s1 = eidx2[beg + i + 1];
        const int s2 = eidx2[beg + i + 2], s3 = eidx2[beg + i + 3];
        const int s4 = eidx2[beg + i + 4], s5 = eidx2[beg + i + 5];
        const int s6 = eidx2[beg + i + 6], s7 = eidx2[beg + i + 7];
        acc += bf2f(hwb[(size_t)s0 * MF + lane]);
        acc += bf2f(hwb[(size_t)s1 * MF + lane]);
        acc += bf2f(hwb[(size_t)s2 * MF + lane]);
        acc += bf2f(hwb[(size_t)s3 * MF + lane]);
        acc += bf2f(hwb[(size_t)s4 * MF + lane]);
        acc += bf2f(hwb[(size_t)s5 * MF + lane]);
        acc += bf2f(hwb[(size_t)s6 * MF + lane]);
        acc += bf2f(hwb[(size_t)s7 * MF + lane]);
      }
      for (; i < e0i; ++i) acc += bf2f(hwb[(size_t)eidx2[beg + i] * MF + lane]);
    }
    const float o = acc * norm[vtx] + bi;
    out[(size_t)vtx * MF + lane] = fmaxf(o, 0.f);
  }
}

extern "C" void kernel_launch(void* const* d_in, const int* in_sizes, int n_in,
                              void* d_out, int out_size, void* d_ws, size_t ws_size,
                              hipStream_t stream) {
  const float* h = (const float*)d_in[0];
  const float* norm = (const float*)d_in[1];
  const float* W = (const float*)d_in[2];
  const float* bias = (const float*)d_in[3];
  const int* src = (const int*)d_in[4];
  const int* dst = (const int*)d_in[5];
  float* out = (float*)d_out;

  unsigned short* hwb = (unsigned short*)d_ws;       // NN*MF bf16 (6.4 MB)
  unsigned short* wtab = hwb + (size_t)NN * MF;      // 16384 bf16 (32 KB)
  int* histT = (int*)(wtab + 16384);                 // NBK*64
  int* bucketStart = histT + NBK * 64;               // NBK (+pad)
  int* bucketCnt = bucketStart + ((NBK + 15) & ~15);
  int* eidx = bucketCnt + ((NBK + 15) & ~15);        // EIDX_CAP
  int* eidx2 = eidx + ((EIDX_CAP + 15) & ~15);       // EIDX_CAP (fallback only)
  const size_t need =
      ((size_t)NN * MF / 2 + 8192 + NBK * 64 + 2 * ((NBK + 15) & ~15) +
       2 * ((EIDX_CAP + 15) & ~15)) * 4;
  if (ws_size < need) return;

  // BW-light edge pipeline first (absorbs the harness-fill BW window),
  // BW-heavy GEMM late, fused sort+gather last.
  hist_prepack<<<HB + 1, 1024, 0, stream>>>(dst, histT, W, wtab);
  scatter_scan<<<HB, 1024, 0, stream>>>(src, dst, histT, eidx, bucketStart, bucketCnt);
  gemm_mfma<<<GB, 256, 0, stream>>>(h, wtab, norm, hwb);
  sort_gather<<<NBK, 256, 0, stream>>>(bucketStart, bucketCnt, eidx, eidx2,
                                       hwb, norm, bias, out);
}

// Round 11
// 161.580 us; speedup vs baseline: 1.0971x; 1.0971x over previous
//
#include <hip/hip_runtime.h>

#define NN 50000
#define NE 800000
#define KF 256
#define MF 64

#define NBK 782    // node buckets of 64: ceil(50000/64)
#define HB 49      // hist/scatter blocks
#define EPB 16384  // edges per hist/scatter block (49*16384 >= 800000)
#define GB 782     // gemm blocks
#define CAP 1536   // LDS edge capacity per bucket (mean 1024 + ~16 sigma)
#define EIDX_CAP (NE + 16 * NBK)

typedef __attribute__((ext_vector_type(8))) short short8;
typedef __attribute__((ext_vector_type(4))) float f32x4;

static __device__ __forceinline__ unsigned short f2bf(float x) {
  unsigned int u = __float_as_uint(x);
  u += 0x7FFF + ((u >> 16) & 1);  // round-nearest-even
  return (unsigned short)(u >> 16);
}
static __device__ __forceinline__ float bf2f(unsigned short u) {
  return __uint_as_float(((unsigned int)u) << 16);
}

// ------- Fused: edge histogram (blocks 0..48) + W prepack (block 49) -------
__global__ __launch_bounds__(1024) void hist_prepack(
    const int* __restrict__ dst, int* __restrict__ histT,
    const float* __restrict__ W, unsigned short* __restrict__ wtab) {
  const int t = threadIdx.x;
  if (blockIdx.x == HB) {  // ---- prepack branch ----
    for (int f = t; f < 2048; f += 1024) {
      const int m = f & 15;
      const int quad = (f >> 4) & 3;
      const int nt = (f >> 6) & 3;
      const int k0i = f >> 8;
      const int n = nt * 16 + m;
      const int kb = k0i * 32 + quad * 8;
      short8 p;
#pragma unroll
      for (int j = 0; j < 8; ++j) p[j] = (short)f2bf(W[(kb + j) * MF + n]);
      *(short8*)(wtab + (size_t)f * 8) = p;
    }
    return;
  }
  __shared__ int hh[NBK];
  for (int i = t; i < NBK; i += 1024) hh[i] = 0;
  __syncthreads();
  const int base = blockIdx.x * EPB;
#pragma unroll
  for (int i = 0; i < EPB / 1024; ++i) {
    const int e = base + i * 1024 + t;
    if (e < NE) atomicAdd(&hh[dst[e] >> 6], 1);
  }
  __syncthreads();
  for (int i = t; i < NBK; i += 1024) histT[i * 64 + blockIdx.x] = hh[i];
}

// ------- Scatter with integrated scan -------------------------------------
__global__ __launch_bounds__(1024) void scatter_scan(
    const int* __restrict__ src, const int* __restrict__ dst,
    const int* __restrict__ histT, int* __restrict__ eidx,
    int* __restrict__ bucketStart, int* __restrict__ bucketCnt) {
  __shared__ int s[1024];
  __shared__ int cur[NBK];
  const int t = threadIdx.x;
  int tot = 0, mine = 0;
  if (t < NBK) {
    const int* hp = histT + t * 64;
#pragma unroll
    for (int b = 0; b < HB; ++b) {
      const int v = hp[b];
      if (b < (int)blockIdx.x) mine += v;
      tot += v;
    }
  }
  const int pad = (tot + 15) & ~15;  // 64 B-align bucket regions
  s[t] = (t < NBK) ? pad : 0;
  __syncthreads();
  for (int off = 1; off < 1024; off <<= 1) {
    const int a = (t >= off) ? s[t - off] : 0;
    __syncthreads();
    s[t] += a;
    __syncthreads();
  }
  if (t < NBK) {
    const int start = s[t] - pad;
    cur[t] = start + mine;
    if (blockIdx.x == 0) {
      bucketStart[t] = start;
      bucketCnt[t] = tot;
    }
  }
  __syncthreads();
  const int base = blockIdx.x * EPB;
#pragma unroll
  for (int i = 0; i < EPB / 1024; ++i) {
    const int e = base + i * 1024 + t;
    if (e < NE) {
      const int d = dst[e];
      const int pos = atomicAdd(&cur[d >> 6], 1);
      eidx[pos] = (src[e] << 6) | (d & 63);
    }
  }
}

// ------- LDS-free MFMA GEMM, batched A-preload pinned by sched_barrier -----
__global__ __launch_bounds__(256, 4) void gemm_mfma(
    const float* __restrict__ h, const unsigned short* __restrict__ wtab,
    const float* __restrict__ norm, unsigned short* __restrict__ hwb) {
  const int t = threadIdx.x;
  const int lane = t & 63;
  const int wv = t >> 6;       // 0..3
  const int m = lane & 15;
  const int quad = lane >> 4;  // 0..3
  const int row0 = blockIdx.x * 64;
  const int arow = row0 + wv * 16 + m;
  const int rowc = (arow < NN) ? arow : (NN - 1);  // clamp; store is guarded
  const float4* ap = (const float4*)(h + (size_t)rowc * KF + quad * 8);

  float4 a[16];
#pragma unroll
  for (int k = 0; k < 8; ++k) {
    a[2 * k] = ap[k * 8];      // k-step stride: 32 floats = 8 float4
    a[2 * k + 1] = ap[k * 8 + 1];
  }
  __builtin_amdgcn_sched_barrier(0);  // all 16 loads stay above this line

  short8 af[8];
#pragma unroll
  for (int k = 0; k < 8; ++k) {
    const float4 a0 = a[2 * k];
    const float4 a1 = a[2 * k + 1];
    af[k][0] = (short)f2bf(a0.x); af[k][1] = (short)f2bf(a0.y);
    af[k][2] = (short)f2bf(a0.z); af[k][3] = (short)f2bf(a0.w);
    af[k][4] = (short)f2bf(a1.x); af[k][5] = (short)f2bf(a1.y);
    af[k][6] = (short)f2bf(a1.z); af[k][7] = (short)f2bf(a1.w);
  }
  __builtin_amdgcn_sched_barrier(0);  // converts complete before MFMA loop

  f32x4 acc[4];
#pragma unroll
  for (int i = 0; i < 4; ++i) acc[i] = (f32x4){0.f, 0.f, 0.f, 0.f};

  const short8* wp = (const short8*)wtab;
#pragma unroll
  for (int k0i = 0; k0i < 8; ++k0i) {
    const short8* wk = wp + k0i * 4 * 64 + lane;
#pragma unroll
    for (int nt = 0; nt < 4; ++nt) {
      const short8 bf = wk[nt * 64];  // L1/L2-resident 32 KB table
      acc[nt] = __builtin_amdgcn_mfma_f32_16x16x32_bf16(af[k0i], bf, acc[nt], 0, 0, 0);
    }
  }

  // Epilogue: D row = quad*4 + r, col = nt*16 + m
  const int gm0 = row0 + wv * 16 + quad * 4;
  float nrm[4];
#pragma unroll
  for (int r = 0; r < 4; ++r) nrm[r] = (gm0 + r < NN) ? norm[gm0 + r] : 0.f;
#pragma unroll
  for (int nt = 0; nt < 4; ++nt) {
#pragma unroll
    for (int r = 0; r < 4; ++r) {
      const int gm = gm0 + r;
      if (gm < NN) hwb[(size_t)gm * MF + nt * 16 + m] = f2bf(acc[nt][r] * nrm[r]);
    }
  }
}

// ------- Fused per-bucket counting sort (in LDS) + gather + epilogue -------
// 1024 threads: 16 waves -> 12.5K waves total for the gather phase (same
// wave-parallelism as the unfused 12500-block gather). Sorted edge ids stay
// in LDS; guaranteed-correct global fallback if cnt > CAP.
__global__ __launch_bounds__(1024) void sort_gather(
    const int* __restrict__ bucketStart, const int* __restrict__ bucketCnt,
    const int* __restrict__ eidx, int* __restrict__ eidx2,
    const unsigned short* __restrict__ hwb, const float* __restrict__ norm,
    const float* __restrict__ bias, float* __restrict__ out) {
  __shared__ int hcnt[64];   // histogram -> node end (after scan)
  __shared__ int sBeg[64];   // node start (local)
  __shared__ int sCur[64];
  __shared__ int sE[CAP];
  const int t = threadIdx.x;
  const int g = blockIdx.x;
  const int beg = __builtin_amdgcn_readfirstlane(bucketStart[g]);
  const int cnt = __builtin_amdgcn_readfirstlane(bucketCnt[g]);
  if (t < 64) hcnt[t] = 0;
  __syncthreads();
  for (int i = t; i < cnt; i += 1024) atomicAdd(&hcnt[eidx[beg + i] & 63], 1);
  __syncthreads();
  if (t < 64) {  // wave 0: exclusive scan of 64 counts
    const int v = hcnt[t];
    int incl = v;
#pragma unroll
    for (int off = 1; off < 64; off <<= 1) {
      const int u = __shfl_up(incl, off, 64);
      if (t >= off) incl += u;
    }
    const int excl = incl - v;
    sBeg[t] = excl;
    sCur[t] = excl;
    hcnt[t] = excl + v;  // end
  }
  __syncthreads();
  const bool inLds = (cnt <= CAP);
  for (int i = t; i < cnt; i += 1024) {
    const int val = eidx[beg + i];
    const int p = atomicAdd(&sCur[val & 63], 1);
    if (inLds) sE[p] = val >> 6;
    else eidx2[beg + p] = val >> 6;
  }
  __syncthreads();

  const int lane = t & 63;
  const int wv = t >> 6;  // 0..15; wave handles nodes wv, wv+16, wv+32, wv+48
  const float bi = bias[lane];
#pragma unroll
  for (int nl = wv; nl < 64; nl += 16) {
    const int vtx = g * 64 + nl;
    if (vtx >= NN) continue;
    const int s0i = __builtin_amdgcn_readfirstlane(sBeg[nl]);
    const int e0i = __builtin_amdgcn_readfirstlane(hcnt[nl]);
    float acc = 0.f;
    int i = s0i;
    if (inLds) {
      for (; i + 8 <= e0i; i += 8) {  // 8 row-loads in flight
        const int s0 = sE[i], s1 = sE[i + 1], s2 = sE[i + 2], s3 = sE[i + 3];
        const int s4 = sE[i + 4], s5 = sE[i + 5], s6 = sE[i + 6], s7 = sE[i + 7];
        const unsigned short x0 = hwb[(size_t)s0 * MF + lane];
        const unsigned short x1 = hwb[(size_t)s1 * MF + lane];
        const unsigned short x2 = hwb[(size_t)s2 * MF + lane];
        const unsigned short x3 = hwb[(size_t)s3 * MF + lane];
        const unsigned short x4 = hwb[(size_t)s4 * MF + lane];
        const unsigned short x5 = hwb[(size_t)s5 * MF + lane];
        const unsigned short x6 = hwb[(size_t)s6 * MF + lane];
        const unsigned short x7 = hwb[(size_t)s7 * MF + lane];
        acc += bf2f(x0); acc += bf2f(x1); acc += bf2f(x2); acc += bf2f(x3);
        acc += bf2f(x4); acc += bf2f(x5); acc += bf2f(x6); acc += bf2f(x7);
      }
      for (; i < e0i; ++i) acc += bf2f(hwb[(size_t)sE[i] * MF + lane]);
    } else {
      for (; i + 8 <= e0i; i += 8) {
        const int s0 = eidx2[beg + i], s1 = eidx2[beg + i + 1];
        const int s2 = eidx2[beg + i + 2], s3 = eidx2[beg + i + 3];
        const int s4 = eidx2[beg + i + 4], s5 = eidx2[beg + i + 5];
        const int s6 = eidx2[beg + i + 6], s7 = eidx2[beg + i + 7];
        acc += bf2f(hwb[(size_t)s0 * MF + lane]);
        acc += bf2f(hwb[(size_t)s1 * MF + lane]);
        acc += bf2f(hwb[(size_t)s2 * MF + lane]);
        acc += bf2f(hwb[(size_t)s3 * MF + lane]);
        acc += bf2f(hwb[(size_t)s4 * MF + lane]);
        acc += bf2f(hwb[(size_t)s5 * MF + lane]);
        acc += bf2f(hwb[(size_t)s6 * MF + lane]);
        acc += bf2f(hwb[(size_t)s7 * MF + lane]);
      }
      for (; i < e0i; ++i) acc += bf2f(hwb[(size_t)eidx2[beg + i] * MF + lane]);
    }
    const float o = acc * norm[vtx] + bi;
    out[(size_t)vtx * MF + lane] = fmaxf(o, 0.f);
  }
}

extern "C" void kernel_launch(void* const* d_in, const int* in_sizes, int n_in,
                              void* d_out, int out_size, void* d_ws, size_t ws_size,
                              hipStream_t stream) {
  const float* h = (const float*)d_in[0];
  const float* norm = (const float*)d_in[1];
  const float* W = (const float*)d_in[2];
  const float* bias = (const float*)d_in[3];
  const int* src = (const int*)d_in[4];
  const int* dst = (const int*)d_in[5];
  float* out = (float*)d_out;

  unsigned short* hwb = (unsigned short*)d_ws;       // NN*MF bf16 (6.4 MB)
  unsigned short* wtab = hwb + (size_t)NN * MF;      // 16384 bf16 (32 KB)
  int* histT = (int*)(wtab + 16384);                 // NBK*64
  int* bucketStart = histT + NBK * 64;               // NBK (+pad)
  int* bucketCnt = bucketStart + ((NBK + 15) & ~15);
  int* eidx = bucketCnt + ((NBK + 15) & ~15);        // EIDX_CAP
  int* eidx2 = eidx + ((EIDX_CAP + 15) & ~15);       // EIDX_CAP (fallback only)
  const size_t need =
      ((size_t)NN * MF / 2 + 8192 + NBK * 64 + 2 * ((NBK + 15) & ~15) +
       2 * ((EIDX_CAP + 15) & ~15)) * 4;
  if (ws_size < need) return;

  // BW-light edge pipeline first (absorbs the harness-fill BW window),
  // BW-heavy GEMM late, fused sort+gather last.
  hist_prepack<<<HB + 1, 1024, 0, stream>>>(dst, histT, W, wtab);
  scatter_scan<<<HB, 1024, 0, stream>>>(src, dst, histT, eidx, bucketStart, bucketCnt);
  gemm_mfma<<<GB, 256, 0, stream>>>(h, wtab, norm, hwb);
  sort_gather<<<NBK, 1024, 0, stream>>>(bucketStart, bucketCnt, eidx, eidx2,
                                        hwb, norm, bias, out);
}

// Round 12
// 149.912 us; speedup vs baseline: 1.1824x; 1.0778x over previous
//
#include <hip/hip_runtime.h>

#define NN 50000
#define NE 800000
#define KF 256
#define MF 64

#define NBK 782    // node buckets of 64: ceil(50000/64)
#define HB 49      // hist/scatter blocks
#define EPB 16384  // edges per hist/scatter block (49*16384 >= 800000)
#define CAP 1536   // LDS edge capacity per bucket (mean 1024 + ~16 sigma)
#define GEMMB 196  // gemm blocks: each does 256 rows (4 tiles of 64)
#define EIDX_CAP (NE + 16 * NBK)

typedef __attribute__((ext_vector_type(8))) short short8;
typedef __attribute__((ext_vector_type(4))) float f32x4;

static __device__ __forceinline__ unsigned short f2bf(float x) {
  unsigned int u = __float_as_uint(x);
  u += 0x7FFF + ((u >> 16) & 1);  // round-nearest-even
  return (unsigned short)(u >> 16);
}
static __device__ __forceinline__ float bf2f(unsigned short u) {
  return __uint_as_float(((unsigned int)u) << 16);
}

// ------- Fused: edge histogram (blocks 0..48) + W prepack (block 49) -------
__global__ __launch_bounds__(1024) void hist_prepack(
    const int* __restrict__ dst, int* __restrict__ histT,
    const float* __restrict__ W, unsigned short* __restrict__ wtab) {
  const int t = threadIdx.x;
  if (blockIdx.x == HB) {  // ---- prepack branch ----
    for (int f = t; f < 2048; f += 1024) {
      const int m = f & 15;
      const int quad = (f >> 4) & 3;
      const int nt = (f >> 6) & 3;
      const int k0i = f >> 8;
      const int n = nt * 16 + m;
      const int kb = k0i * 32 + quad * 8;
      short8 p;
#pragma unroll
      for (int j = 0; j < 8; ++j) p[j] = (short)f2bf(W[(kb + j) * MF + n]);
      *(short8*)(wtab + (size_t)f * 8) = p;
    }
    return;
  }
  __shared__ int hh[NBK];
  for (int i = t; i < NBK; i += 1024) hh[i] = 0;
  __syncthreads();
  const int base = blockIdx.x * EPB;
#pragma unroll
  for (int i = 0; i < EPB / 1024; ++i) {
    const int e = base + i * 1024 + t;
    if (e < NE) atomicAdd(&hh[dst[e] >> 6], 1);
  }
  __syncthreads();
  for (int i = t; i < NBK; i += 1024) histT[i * 64 + blockIdx.x] = hh[i];
}

// ------- Fused: scatter_scan (blocks 0..48) + MFMA GEMM (49..244) ----------
// Two independent pipeline chains overlapped in one dispatch: scatter is
// latency-bound (LDS atomics), gemm is BW/MFMA-bound -> co-scheduling gives
// ~max instead of sum. 245 blocks, all co-resident.
__global__ __launch_bounds__(1024, 4) void scatter_gemm(
    const int* __restrict__ src, const int* __restrict__ dst,
    const int* __restrict__ histT, int* __restrict__ eidx,
    int* __restrict__ bucketStart, int* __restrict__ bucketCnt,
    const float* __restrict__ h, const unsigned short* __restrict__ wtab,
    const float* __restrict__ norm, unsigned short* __restrict__ hwb) {
  const int t = threadIdx.x;

  if (blockIdx.x >= HB) {  // ---- GEMM branch: 4 x 64-row tiles ----
    const int sub = t >> 8;        // 0..3
    const int tt = t & 255;
    const int lane = tt & 63;
    const int wv = tt >> 6;        // 0..3
    const int m = lane & 15;
    const int quad = lane >> 4;    // 0..3
    const int row0 = (blockIdx.x - HB) * 256 + sub * 64;
    const int arow = row0 + wv * 16 + m;
    const int rowc = (arow < NN) ? arow : (NN - 1);  // clamp; store guarded
    const float4* ap = (const float4*)(h + (size_t)rowc * KF + quad * 8);

    float4 a[16];
#pragma unroll
    for (int k = 0; k < 8; ++k) {
      a[2 * k] = ap[k * 8];        // k-step stride: 32 floats = 8 float4
      a[2 * k + 1] = ap[k * 8 + 1];
    }
    __builtin_amdgcn_sched_barrier(0);  // all 16 loads issue first

    short8 af[8];
#pragma unroll
    for (int k = 0; k < 8; ++k) {
      const float4 a0 = a[2 * k];
      const float4 a1 = a[2 * k + 1];
      af[k][0] = (short)f2bf(a0.x); af[k][1] = (short)f2bf(a0.y);
      af[k][2] = (short)f2bf(a0.z); af[k][3] = (short)f2bf(a0.w);
      af[k][4] = (short)f2bf(a1.x); af[k][5] = (short)f2bf(a1.y);
      af[k][6] = (short)f2bf(a1.z); af[k][7] = (short)f2bf(a1.w);
    }
    __builtin_amdgcn_sched_barrier(0);

    f32x4 acc[4];
#pragma unroll
    for (int i = 0; i < 4; ++i) acc[i] = (f32x4){0.f, 0.f, 0.f, 0.f};

    const short8* wp = (const short8*)wtab;
#pragma unroll
    for (int k0i = 0; k0i < 8; ++k0i) {
      const short8* wk = wp + k0i * 4 * 64 + lane;
#pragma unroll
      for (int nt = 0; nt < 4; ++nt) {
        const short8 bf = wk[nt * 64];  // L1/L2-resident 32 KB table
        acc[nt] = __builtin_amdgcn_mfma_f32_16x16x32_bf16(af[k0i], bf, acc[nt], 0, 0, 0);
      }
    }

    const int gm0 = row0 + wv * 16 + quad * 4;
    float nrm[4];
#pragma unroll
    for (int r = 0; r < 4; ++r) nrm[r] = (gm0 + r < NN) ? norm[gm0 + r] : 0.f;
#pragma unroll
    for (int nt = 0; nt < 4; ++nt) {
#pragma unroll
      for (int r = 0; r < 4; ++r) {
        const int gm = gm0 + r;
        if (gm < NN) hwb[(size_t)gm * MF + nt * 16 + m] = f2bf(acc[nt][r] * nrm[r]);
      }
    }
    return;
  }

  // ---- scatter branch ----
  __shared__ int s[1024];
  __shared__ int cur[NBK];
  int tot = 0, mine = 0;
  if (t < NBK) {
    const int* hp = histT + t * 64;
#pragma unroll
    for (int b = 0; b < HB; ++b) {
      const int v = hp[b];
      if (b < (int)blockIdx.x) mine += v;
      tot += v;
    }
  }
  const int pad = (tot + 15) & ~15;  // 64 B-align bucket regions
  s[t] = (t < NBK) ? pad : 0;
  __syncthreads();
  for (int off = 1; off < 1024; off <<= 1) {
    const int a = (t >= off) ? s[t - off] : 0;
    __syncthreads();
    s[t] += a;
    __syncthreads();
  }
  if (t < NBK) {
    const int start = s[t] - pad;
    cur[t] = start + mine;
    if (blockIdx.x == 0) {
      bucketStart[t] = start;
      bucketCnt[t] = tot;
    }
  }
  __syncthreads();
  const int base = blockIdx.x * EPB;
#pragma unroll
  for (int i = 0; i < EPB / 1024; ++i) {
    const int e = base + i * 1024 + t;
    if (e < NE) {
      const int d = dst[e];
      const int pos = atomicAdd(&cur[d >> 6], 1);
      eidx[pos] = (src[e] << 6) | (d & 63);
    }
  }
}

// ------- Fused per-bucket counting sort (in LDS) + gather + epilogue -------
__global__ __launch_bounds__(1024) void sort_gather(
    const int* __restrict__ bucketStart, const int* __restrict__ bucketCnt,
    const int* __restrict__ eidx, int* __restrict__ eidx2,
    const unsigned short* __restrict__ hwb, const float* __restrict__ norm,
    const float* __restrict__ bias, float* __restrict__ out) {
  __shared__ int hcnt[64];   // histogram -> node end (after scan)
  __shared__ int sBeg[64];   // node start (local)
  __shared__ int sCur[64];
  __shared__ int sE[CAP];
  const int t = threadIdx.x;
  const int g = blockIdx.x;
  const int beg = __builtin_amdgcn_readfirstlane(bucketStart[g]);
  const int cnt = __builtin_amdgcn_readfirstlane(bucketCnt[g]);
  if (t < 64) hcnt[t] = 0;
  __syncthreads();
  for (int i = t; i < cnt; i += 1024) atomicAdd(&hcnt[eidx[beg + i] & 63], 1);
  __syncthreads();
  if (t < 64) {  // wave 0: exclusive scan of 64 counts
    const int v = hcnt[t];
    int incl = v;
#pragma unroll
    for (int off = 1; off < 64; off <<= 1) {
      const int u = __shfl_up(incl, off, 64);
      if (t >= off) incl += u;
    }
    const int excl = incl - v;
    sBeg[t] = excl;
    sCur[t] = excl;
    hcnt[t] = excl + v;  // end
  }
  __syncthreads();
  const bool inLds = (cnt <= CAP);
  for (int i = t; i < cnt; i += 1024) {
    const int val = eidx[beg + i];
    const int p = atomicAdd(&sCur[val & 63], 1);
    if (inLds) sE[p] = val >> 6;
    else eidx2[beg + p] = val >> 6;
  }
  __syncthreads();

  const int lane = t & 63;
  const int wv = t >> 6;  // 0..15; wave handles nodes wv, wv+16, wv+32, wv+48
  const float bi = bias[lane];
#pragma unroll
  for (int nl = wv; nl < 64; nl += 16) {
    const int vtx = g * 64 + nl;
    if (vtx >= NN) continue;
    const int s0i = __builtin_amdgcn_readfirstlane(sBeg[nl]);
    const int e0i = __builtin_amdgcn_readfirstlane(hcnt[nl]);
    float acc = 0.f;
    int i = s0i;
    if (inLds) {
      for (; i + 8 <= e0i; i += 8) {  // 8 row-loads in flight
        const int s0 = sE[i], s1 = sE[i + 1], s2 = sE[i + 2], s3 = sE[i + 3];
        const int s4 = sE[i + 4], s5 = sE[i + 5], s6 = sE[i + 6], s7 = sE[i + 7];
        const unsigned short x0 = hwb[(size_t)s0 * MF + lane];
        const unsigned short x1 = hwb[(size_t)s1 * MF + lane];
        const unsigned short x2 = hwb[(size_t)s2 * MF + lane];
        const unsigned short x3 = hwb[(size_t)s3 * MF + lane];
        const unsigned short x4 = hwb[(size_t)s4 * MF + lane];
        const unsigned short x5 = hwb[(size_t)s5 * MF + lane];
        const unsigned short x6 = hwb[(size_t)s6 * MF + lane];
        const unsigned short x7 = hwb[(size_t)s7 * MF + lane];
        acc += bf2f(x0); acc += bf2f(x1); acc += bf2f(x2); acc += bf2f(x3);
        acc += bf2f(x4); acc += bf2f(x5); acc += bf2f(x6); acc += bf2f(x7);
      }
      for (; i < e0i; ++i) acc += bf2f(hwb[(size_t)sE[i] * MF + lane]);
    } else {
      for (; i + 8 <= e0i; i += 8) {
        const int s0 = eidx2[beg + i], s1 = eidx2[beg + i + 1];
        const int s2 = eidx2[beg + i + 2], s3 = eidx2[beg + i + 3];
        const int s4 = eidx2[beg + i + 4], s5 = eidx2[beg + i + 5];
        const int s6 = eidx2[beg + i + 6], s7 = eidx2[beg + i + 7];
        acc += bf2f(hwb[(size_t)s0 * MF + lane]);
        acc += bf2f(hwb[(size_t)s1 * MF + lane]);
        acc += bf2f(hwb[(size_t)s2 * MF + lane]);
        acc += bf2f(hwb[(size_t)s3 * MF + lane]);
        acc += bf2f(hwb[(size_t)s4 * MF + lane]);
        acc += bf2f(hwb[(size_t)s5 * MF + lane]);
        acc += bf2f(hwb[(size_t)s6 * MF + lane]);
        acc += bf2f(hwb[(size_t)s7 * MF + lane]);
      }
      for (; i < e0i; ++i) acc += bf2f(hwb[(size_t)eidx2[beg + i] * MF + lane]);
    }
    const float o = acc * norm[vtx] + bi;
    out[(size_t)vtx * MF + lane] = fmaxf(o, 0.f);
  }
}

extern "C" void kernel_launch(void* const* d_in, const int* in_sizes, int n_in,
                              void* d_out, int out_size, void* d_ws, size_t ws_size,
                              hipStream_t stream) {
  const float* h = (const float*)d_in[0];
  const float* norm = (const float*)d_in[1];
  const float* W = (const float*)d_in[2];
  const float* bias = (const float*)d_in[3];
  const int* src = (const int*)d_in[4];
  const int* dst = (const int*)d_in[5];
  float* out = (float*)d_out;

  unsigned short* hwb = (unsigned short*)d_ws;       // NN*MF bf16 (6.4 MB)
  unsigned short* wtab = hwb + (size_t)NN * MF;      // 16384 bf16 (32 KB)
  int* histT = (int*)(wtab + 16384);                 // NBK*64
  int* bucketStart = histT + NBK * 64;               // NBK (+pad)
  int* bucketCnt = bucketStart + ((NBK + 15) & ~15);
  int* eidx = bucketCnt + ((NBK + 15) & ~15);        // EIDX_CAP
  int* eidx2 = eidx + ((EIDX_CAP + 15) & ~15);       // EIDX_CAP (fallback only)
  const size_t need =
      ((size_t)NN * MF / 2 + 8192 + NBK * 64 + 2 * ((NBK + 15) & ~15) +
       2 * ((EIDX_CAP + 15) & ~15)) * 4;
  if (ws_size < need) return;

  hist_prepack<<<HB + 1, 1024, 0, stream>>>(dst, histT, W, wtab);
  scatter_gemm<<<HB + GEMMB, 1024, 0, stream>>>(
      src, dst, histT, eidx, bucketStart, bucketCnt, h, wtab, norm, hwb);
  sort_gather<<<NBK, 1024, 0, stream>>>(bucketStart, bucketCnt, eidx, eidx2,
                                        hwb, norm, bias, out);
}